// Round 8
// baseline (256.195 us; speedup 1.0000x reference)
//
#include <hip/hip_runtime.h>
#include <math.h>

// L = diag((W+W^T).sum(1)) - (W+W^T), cotangent weights per face.
//
// Producer-consumer in ONE kernel (no grid sync, no coop launch):
//   node 1: memset 66KB of d_ws (done counter + cnt[] + diag[])
//   node 2: grid = NBIN bin-blocks (first) + N/RPB fill-blocks.
//     bin:  1 face/thread -> cot weights -> push (col,-v) into per-row global
//           buckets via device-scope atomics + diag atomicAdd; threadfence;
//           bump done counter.
//     fill: owns RPB rows. Zeroes them with pure coalesced v4f stores
//           (~38us, hides the ~3us binning), barrier, acquire-spin on
//           done==nF (instant by then), then per row: stage <=CAP+1 entries
//           in LDS, O(k^2) dedup-merge, plain-store merged values.
// Output lines are each written by exactly one block; no atomics on d_out.
// Bounded-spin fallback (direct face scan) removes any dispatch-order hazard.

#define CAP   64          // bucket entries/row (mean ~12; fixed mesh max << 64)
#define RPB   4           // rows per fill block
#define SPIN_LIMIT 3000000

typedef float v4f __attribute__((ext_vector_type(4)));

__device__ __forceinline__ void cot_weights(const float* __restrict__ V,
                                            int i0, int i1, int i2,
                                            float& c0, float& c1, float& c2) {
    const float ax = V[i0 * 3 + 0], ay = V[i0 * 3 + 1], az = V[i0 * 3 + 2];
    const float bx = V[i1 * 3 + 0], by = V[i1 * 3 + 1], bz = V[i1 * 3 + 2];
    const float cx = V[i2 * 3 + 0], cy = V[i2 * 3 + 1], cz = V[i2 * 3 + 2];

    float dx, dy, dz, d2;
    dx = bx - cx; dy = by - cy; dz = bz - cz;
    d2 = dx * dx + dy * dy + dz * dz;
    const float l1 = (d2 > 0.0f) ? sqrtf(d2) : 0.0f;
    dx = cx - ax; dy = cy - ay; dz = cz - az;
    d2 = dx * dx + dy * dy + dz * dz;
    const float l2 = (d2 > 0.0f) ? sqrtf(d2) : 0.0f;
    dx = ax - bx; dy = ay - by; dz = az - bz;
    d2 = dx * dx + dy * dy + dz * dz;
    const float l3 = (d2 > 0.0f) ? sqrtf(d2) : 0.0f;

    const float sp = (l1 + l2 + l3) * 0.5f;
    const float s  = sp * (sp - l1) * (sp - l2) * (sp - l3);
    const float A  = (s > 0.0f) ? 2.0f * sqrtf(s) : 1.0f;

    c0 = ((l2 * l2 + l3 * l3 - l1 * l1) / A) * 0.25f; // (r=i1, c=i2)
    c1 = ((l1 * l1 + l3 * l3 - l2 * l2) / A) * 0.25f; // (r=i2, c=i0)
    c2 = ((l1 * l1 + l2 * l2 - l3 * l3) / A) * 0.25f; // (r=i0, c=i1)
}

__device__ __forceinline__ void read_face(const int* __restrict__ Fw, int f,
                                          bool is64, int& i0, int& i1, int& i2) {
    if (is64) { i0 = Fw[f * 6]; i1 = Fw[f * 6 + 2]; i2 = Fw[f * 6 + 4]; }
    else      { i0 = Fw[f * 3]; i1 = Fw[f * 3 + 1]; i2 = Fw[f * 3 + 2]; }
}

// N must be 8192. nbin = ceil(nF/256). ws layout (words):
//   [0]        done
//   [64 ..)    cnt[8192]
//   [8256 ..)  diag[8192]
//   [16448 ..) cols[8192*CAP]
//   [16448+8192*CAP ..) vals[8192*CAP]
__global__ __launch_bounds__(256) void lap_fused_kernel(
        const float* __restrict__ V, const int* __restrict__ Fw,
        float* __restrict__ L, int* __restrict__ ws, int nF, int nbin) {
    int*   done = ws;
    int*   cnt  = ws + 64;
    float* diag = (float*)(ws + 64 + 8192);
    int*   cols = ws + 64 + 2 * 8192;
    float* vals = (float*)(ws + 64 + 2 * 8192 + 8192 * CAP);

    const int tid = threadIdx.x;
    const int bid = blockIdx.x;

    const bool is64 = (Fw[1] == 0) && (Fw[3] == 0) && (Fw[5] == 0) &&
                      (Fw[7] == 0) && (Fw[9] == 0) && (Fw[11] == 0);

    if (bid < nbin) {
        // ---------------- bin block: one face per thread ----------------
        const int f = bid * 256 + tid;
        if (f < nF) {
            int i0, i1, i2;
            read_face(Fw, f, is64, i0, i1, i2);
            float c0, c1, c2;
            cot_weights(V, i0, i1, i2, c0, c1, c2);

            const int rr_[3] = {i1, i2, i0};
            const int cc_[3] = {i2, i0, i1};
            const float vv_[3] = {c0, c1, c2};
#pragma unroll
            for (int t = 0; t < 3; ++t) {
                const int r = rr_[t], c = cc_[t];
                const float v = vv_[t];
                int s = atomicAdd(&cnt[r], 1);
                if (s < CAP) {
                    atomicExch(&cols[r * CAP + s], c);
                    atomicExch(&vals[r * CAP + s], -v);
                }
                s = atomicAdd(&cnt[c], 1);
                if (s < CAP) {
                    atomicExch(&cols[c * CAP + s], r);
                    atomicExch(&vals[c * CAP + s], -v);
                }
                atomicAdd(&diag[r], v);
                atomicAdd(&diag[c], v);
            }
        }
        __threadfence();            // release: buckets visible device-wide
        atomicAdd(done, 1);         // one tick per thread (target = nbin*256)
        return;
    }

    // ---------------- fill block: owns RPB rows ----------------
    __shared__ int   ec[CAP + 1];
    __shared__ float ev[CAP + 1];
    __shared__ float ac[CAP + 1];
    __shared__ int   s_timeout;

    const int r0 = (bid - nbin) * RPB;

    // phase 1: zero my rows (pure coalesced 16B stores; this is ~95% of the
    // kernel and completely hides the binning running on other blocks)
#pragma unroll
    for (int rl = 0; rl < RPB; ++rl) {
        v4f* rp = (v4f*)(L + (size_t)(r0 + rl) * 8192);
#pragma unroll
        for (int i = 0; i < 8; ++i)
            rp[tid + (i << 8)] = (v4f)0.0f;
    }
    __syncthreads();   // drain zero-stores (vmcnt) before overwrite below

    // phase 2: wait for producers (instant in practice)
    if (tid == 0) {
        const int target = nbin * 256;
        int spins = 0, ok = 0;
        while (spins < SPIN_LIMIT) {
            if (__hip_atomic_load(done, __ATOMIC_ACQUIRE,
                                  __HIP_MEMORY_SCOPE_AGENT) >= target) { ok = 1; break; }
            ++spins;
        }
        s_timeout = !ok;
        __threadfence();
    }
    __syncthreads();

    if (!s_timeout) {
        // phase 3: per row, merge bucket entries (dedup) + diag, plain stores
        for (int rl = 0; rl < RPB; ++rl) {
            const int row = r0 + rl;
            int k = cnt[row];
            if (k > CAP) k = CAP;

            if (tid < k) { ec[tid] = cols[row * CAP + tid]; ev[tid] = vals[row * CAP + tid]; }
            if (tid == k) { ec[tid] = row; ev[tid] = diag[row]; }   // diag entry
            const int kk = k + 1;
            __syncthreads();
            if (tid < kk) ac[tid] = ev[tid];
            __syncthreads();
            int fo = tid;
            if (tid < kk) {
                for (int j = 0; j < tid; ++j)
                    if (ec[j] == ec[tid]) { fo = j; break; }
                if (fo != tid) atomicAdd(&ac[fo], ev[tid]);   // LDS atomic
            }
            __syncthreads();
            if (tid < kk && fo == tid)
                L[(size_t)row * 8192 + ec[tid]] = ac[tid];
            __syncthreads();
        }
        return;
    }

    // ---- timeout fallback (provably correct, never runs in practice):
    // derive my rows directly from a full face scan, register-accumulate.
#define CASE_(i) case i: o[i] += v; break;
    for (int rl = 0; rl < RPB; ++rl) {
        const int row = r0 + rl;
        float o[32];
#pragma unroll
        for (int i = 0; i < 32; ++i) o[i] = 0.0f;
        float dsum = 0.0f;

        for (int f = 0; f < nF; ++f) {
            int i0, i1, i2;
            read_face(Fw, f, is64, i0, i1, i2);
            if (i0 != row && i1 != row && i2 != row) continue;
            float c0, c1, c2;
            cot_weights(V, i0, i1, i2, c0, c1, c2);
            const int rr_[3] = {i1, i2, i0};
            const int cc_[3] = {i2, i0, i1};
            const float vv_[3] = {c0, c1, c2};
#pragma unroll
            for (int t = 0; t < 3; ++t) {
                const int r = rr_[t], c = cc_[t];
                const float vw = vv_[t];
                int col = -1;
                if (r == row) { col = c; dsum += vw; }
                else if (c == row) { col = r; dsum += vw; }
                if (col >= 0 && ((col >> 2) & 255) == tid) {
                    const float v = -vw;
                    const int idx = ((col >> 10) << 2) | (col & 3);
                    switch (idx) {
                        CASE_(0)  CASE_(1)  CASE_(2)  CASE_(3)
                        CASE_(4)  CASE_(5)  CASE_(6)  CASE_(7)
                        CASE_(8)  CASE_(9)  CASE_(10) CASE_(11)
                        CASE_(12) CASE_(13) CASE_(14) CASE_(15)
                        CASE_(16) CASE_(17) CASE_(18) CASE_(19)
                        CASE_(20) CASE_(21) CASE_(22) CASE_(23)
                        CASE_(24) CASE_(25) CASE_(26) CASE_(27)
                        CASE_(28) CASE_(29) CASE_(30) CASE_(31)
                    }
                }
            }
        }
        // diagonal: add to owner of col==row
        if (((row >> 2) & 255) == tid) {
            const float v = dsum;
            const int idx = ((row >> 10) << 2) | (row & 3);
            switch (idx) {
                CASE_(0)  CASE_(1)  CASE_(2)  CASE_(3)
                CASE_(4)  CASE_(5)  CASE_(6)  CASE_(7)
                CASE_(8)  CASE_(9)  CASE_(10) CASE_(11)
                CASE_(12) CASE_(13) CASE_(14) CASE_(15)
                CASE_(16) CASE_(17) CASE_(18) CASE_(19)
                CASE_(20) CASE_(21) CASE_(22) CASE_(23)
                CASE_(24) CASE_(25) CASE_(26) CASE_(27)
                CASE_(28) CASE_(29) CASE_(30) CASE_(31)
            }
        }
        float* rowp = L + (size_t)row * 8192;
#pragma unroll
        for (int i = 0; i < 8; ++i) {
            v4f t;
            t[0] = o[4 * i + 0]; t[1] = o[4 * i + 1];
            t[2] = o[4 * i + 2]; t[3] = o[4 * i + 3];
            *(v4f*)(rowp + 4 * (tid + (i << 8))) = t;
        }
    }
#undef CASE_
}

// ---- generic fallback (N != 8192 or ws too small): memset + scatter ----
__global__ __launch_bounds__(256) void corner_scatter_kernel(
        const float* __restrict__ V, const int* __restrict__ Fw,
        float* __restrict__ L, int nF, int N) {
    const int g = blockIdx.x * 256 + threadIdx.x;
    if (g >= nF * 3) return;
    const int f = g / 3;
    const int t = g - f * 3;

    const bool is64 = (Fw[1] == 0) && (Fw[3] == 0) && (Fw[5] == 0) &&
                      (Fw[7] == 0) && (Fw[9] == 0) && (Fw[11] == 0);
    int i0, i1, i2;
    read_face(Fw, f, is64, i0, i1, i2);

    float c0, c1, c2;
    cot_weights(V, i0, i1, i2, c0, c1, c2);

    const float num = (t == 0) ? c0 : (t == 1) ? c1 : c2;
    const int r = (t == 0) ? i1 : (t == 1) ? i2 : i0;
    const int c = (t == 0) ? i2 : (t == 1) ? i0 : i1;

    const size_t n = (size_t)N;
    atomicAdd(&L[(size_t)r * n + c], -num);
    atomicAdd(&L[(size_t)c * n + r], -num);
    atomicAdd(&L[(size_t)r * n + r],  num);
    atomicAdd(&L[(size_t)c * n + c],  num);
}

extern "C" void kernel_launch(void* const* d_in, const int* in_sizes, int n_in,
                              void* d_out, int out_size, void* d_ws, size_t ws_size,
                              hipStream_t stream) {
    const float* V = (const float*)d_in[0];
    const int* Fw  = (const int*)d_in[1];
    float* L       = (float*)d_out;

    const int N  = in_sizes[0] / 3;   // 8192 vertices
    const int nF = in_sizes[1] / 3;   // 16384 faces

    // ws words needed: 64 + 2*8192 + 2*8192*CAP
    const size_t need_bytes = (size_t)(64 + 2 * 8192 + 2 * 8192 * CAP) * 4;

    if (N == 8192 && ws_size >= need_bytes) {
        const int nbin = (nF + 255) / 256;
        // node 1: zero done + cnt + diag (66KB prefix of ws)
        hipMemsetAsync(d_ws, 0, (size_t)(64 + 2 * 8192) * 4, stream);
        // node 2: fused bin + zero/merge-fill kernel
        const int grid = nbin + 8192 / RPB;
        lap_fused_kernel<<<grid, 256, 0, stream>>>(V, Fw, L, (int*)d_ws, nF, nbin);
    } else {
        hipMemsetAsync(d_out, 0, (size_t)out_size * sizeof(float), stream);
        const int total = nF * 3;
        corner_scatter_kernel<<<(total + 255) / 256, 256, 0, stream>>>(V, Fw, L, nF, N);
    }
}

// Round 9
// 59.476 us; speedup vs baseline: 4.3076x; 4.3076x over previous
//
#include <hip/hip_runtime.h>
#include <math.h>

// L = diag((W+W^T).sum(1)) - (W+W^T), cotangent weights per face.
// 3-node pipeline, no 268MB memset:
//   node 1: memset 64KB (cnt + diag) in ws
//   node 2: bin_faces - per-face cot weights, append (col,-v) pairs into
//           per-row buckets in ws (L2-resident), diag atomicAdds
//   node 3: fill - ONE ROW PER BLOCK, near-pure store kernel: stage <=65
//           entries in LDS, each thread switch-accumulates its hits into
//           32 registers (dups accumulate => no dedup), then 8 coalesced
//           float4 stores. The 268MB output is written exactly once.

#define CAP 64   // bucket entries/row; mean ~13, P(>64) astronomically small

typedef float v4f __attribute__((ext_vector_type(4)));

__device__ __forceinline__ void cot_weights(const float* __restrict__ V,
                                            int i0, int i1, int i2,
                                            float& c0, float& c1, float& c2) {
    const float ax = V[i0 * 3 + 0], ay = V[i0 * 3 + 1], az = V[i0 * 3 + 2];
    const float bx = V[i1 * 3 + 0], by = V[i1 * 3 + 1], bz = V[i1 * 3 + 2];
    const float cx = V[i2 * 3 + 0], cy = V[i2 * 3 + 1], cz = V[i2 * 3 + 2];

    float dx, dy, dz, d2;
    dx = bx - cx; dy = by - cy; dz = bz - cz;
    d2 = dx * dx + dy * dy + dz * dz;
    const float l1 = (d2 > 0.0f) ? sqrtf(d2) : 0.0f;
    dx = cx - ax; dy = cy - ay; dz = cz - az;
    d2 = dx * dx + dy * dy + dz * dz;
    const float l2 = (d2 > 0.0f) ? sqrtf(d2) : 0.0f;
    dx = ax - bx; dy = ay - by; dz = az - bz;
    d2 = dx * dx + dy * dy + dz * dz;
    const float l3 = (d2 > 0.0f) ? sqrtf(d2) : 0.0f;

    const float sp = (l1 + l2 + l3) * 0.5f;
    const float s  = sp * (sp - l1) * (sp - l2) * (sp - l3);
    const float A  = (s > 0.0f) ? 2.0f * sqrtf(s) : 1.0f;

    c0 = ((l2 * l2 + l3 * l3 - l1 * l1) / A) * 0.25f; // (r=i1, c=i2)
    c1 = ((l1 * l1 + l3 * l3 - l2 * l2) / A) * 0.25f; // (r=i2, c=i0)
    c2 = ((l1 * l1 + l2 * l2 - l3 * l3) / A) * 0.25f; // (r=i0, c=i1)
}

__device__ __forceinline__ void read_face(const int* __restrict__ Fw, int f,
                                          bool is64, int& i0, int& i1, int& i2) {
    if (is64) { i0 = Fw[f * 6]; i1 = Fw[f * 6 + 2]; i2 = Fw[f * 6 + 4]; }
    else      { i0 = Fw[f * 3]; i1 = Fw[f * 3 + 1]; i2 = Fw[f * 3 + 2]; }
}

// ws layout (words): cnt[8192] | diag[8192] | pairs[8192*CAP*2] (col,val)
__global__ __launch_bounds__(256) void bin_faces_kernel(
        const float* __restrict__ V, const int* __restrict__ Fw,
        int* __restrict__ cnt, float* __restrict__ diag,
        int* __restrict__ pairs, int nF) {
    const int f = blockIdx.x * 256 + threadIdx.x;
    if (f >= nF) return;

    const bool is64 = (Fw[1] == 0) && (Fw[3] == 0) && (Fw[5] == 0) &&
                      (Fw[7] == 0) && (Fw[9] == 0) && (Fw[11] == 0);

    int i0, i1, i2;
    read_face(Fw, f, is64, i0, i1, i2);
    float c0, c1, c2;
    cot_weights(V, i0, i1, i2, c0, c1, c2);

    const int rr_[3] = {i1, i2, i0};
    const int cc_[3] = {i2, i0, i1};
    const float vv_[3] = {c0, c1, c2};
#pragma unroll
    for (int t = 0; t < 3; ++t) {
        const int r = rr_[t], c = cc_[t];
        const float v = vv_[t];
        int s = atomicAdd(&cnt[r], 1);
        if (s < CAP) {
            int* p = pairs + (size_t)(r * CAP + s) * 2;
            p[0] = c; ((float*)p)[1] = -v;
        }
        s = atomicAdd(&cnt[c], 1);
        if (s < CAP) {
            int* p = pairs + (size_t)(c * CAP + s) * 2;
            p[0] = r; ((float*)p)[1] = -v;
        }
        atomicAdd(&diag[r], v);
        atomicAdd(&diag[c], v);
    }
}

// One row (8192 floats) per block; N must be 8192.
__global__ __launch_bounds__(256) void fill_rows_kernel(
        const int* __restrict__ cnt, const float* __restrict__ diag,
        const int* __restrict__ pairs, float* __restrict__ L) {
    __shared__ int   ec[CAP + 1];
    __shared__ float ev[CAP + 1];

    const int row = blockIdx.x;
    const int tid = threadIdx.x;

    int k = cnt[row];                      // same-address load -> broadcast
    if (k > CAP) k = CAP;
    if (tid < k) {
        const int* p = pairs + (size_t)(row * CAP + tid) * 2;
        ec[tid] = p[0];
        ev[tid] = ((const float*)p)[1];
    }
    if (tid == k) { ec[tid] = row; ev[tid] = diag[row]; }  // diagonal entry
    __syncthreads();

    float o[32];
#pragma unroll
    for (int i = 0; i < 32; ++i) o[i] = 0.0f;

    const int kk = k + 1;
#define CASE_(i) case i: o[i] += v; break;
    for (int e = 0; e < kk; ++e) {
        const int   c = ec[e];             // uniform LDS broadcast
        const float v = ev[e];
        if (((c >> 2) & 255) == tid) {     // exactly one owner thread
            const int idx = ((c >> 10) << 2) | (c & 3);   // static 0..31
            switch (idx) {
                CASE_(0)  CASE_(1)  CASE_(2)  CASE_(3)
                CASE_(4)  CASE_(5)  CASE_(6)  CASE_(7)
                CASE_(8)  CASE_(9)  CASE_(10) CASE_(11)
                CASE_(12) CASE_(13) CASE_(14) CASE_(15)
                CASE_(16) CASE_(17) CASE_(18) CASE_(19)
                CASE_(20) CASE_(21) CASE_(22) CASE_(23)
                CASE_(24) CASE_(25) CASE_(26) CASE_(27)
                CASE_(28) CASE_(29) CASE_(30) CASE_(31)
            }
        }
    }
#undef CASE_

    // duplicate columns accumulated above -> single coalesced store pass
    float* rowp = L + (size_t)row * 8192;
#pragma unroll
    for (int g = 0; g < 8; ++g) {
        v4f t;
        t[0] = o[4 * g + 0]; t[1] = o[4 * g + 1];
        t[2] = o[4 * g + 2]; t[3] = o[4 * g + 3];
        *(v4f*)(rowp + 4 * (tid + (g << 8))) = t;
    }
}

// ---- generic fallback (N != 8192 or ws too small): memset + scatter ----
__global__ __launch_bounds__(256) void corner_scatter_kernel(
        const float* __restrict__ V, const int* __restrict__ Fw,
        float* __restrict__ L, int nF, int N) {
    const int g = blockIdx.x * 256 + threadIdx.x;
    if (g >= nF * 3) return;
    const int f = g / 3;
    const int t = g - f * 3;

    const bool is64 = (Fw[1] == 0) && (Fw[3] == 0) && (Fw[5] == 0) &&
                      (Fw[7] == 0) && (Fw[9] == 0) && (Fw[11] == 0);
    int i0, i1, i2;
    read_face(Fw, f, is64, i0, i1, i2);

    float c0, c1, c2;
    cot_weights(V, i0, i1, i2, c0, c1, c2);

    const float num = (t == 0) ? c0 : (t == 1) ? c1 : c2;
    const int r = (t == 0) ? i1 : (t == 1) ? i2 : i0;
    const int c = (t == 0) ? i2 : (t == 1) ? i0 : i1;

    const size_t n = (size_t)N;
    atomicAdd(&L[(size_t)r * n + c], -num);
    atomicAdd(&L[(size_t)c * n + r], -num);
    atomicAdd(&L[(size_t)r * n + r],  num);
    atomicAdd(&L[(size_t)c * n + c],  num);
}

extern "C" void kernel_launch(void* const* d_in, const int* in_sizes, int n_in,
                              void* d_out, int out_size, void* d_ws, size_t ws_size,
                              hipStream_t stream) {
    const float* V = (const float*)d_in[0];
    const int* Fw  = (const int*)d_in[1];
    float* L       = (float*)d_out;

    const int N  = in_sizes[0] / 3;   // 8192 vertices
    const int nF = in_sizes[1] / 3;   // 16384 faces

    // ws words: cnt 8192 + diag 8192 + pairs 8192*CAP*2
    const size_t need_bytes = (size_t)(2 * 8192 + 8192 * CAP * 2) * 4;

    if (N == 8192 && ws_size >= need_bytes) {
        int*   cnt   = (int*)d_ws;
        float* diag  = (float*)((char*)d_ws + 8192 * 4);
        int*   pairs = (int*)((char*)d_ws + 2 * 8192 * 4);

        // node 1: zero cnt + diag (64KB)
        hipMemsetAsync(d_ws, 0, (size_t)(2 * 8192) * 4, stream);
        // node 2: bin (appends pairs; no need to pre-zero the pair region)
        bin_faces_kernel<<<(nF + 255) / 256, 256, 0, stream>>>(
            V, Fw, cnt, diag, pairs, nF);
        // node 3: fill (one row per block, near-pure stores)
        fill_rows_kernel<<<8192, 256, 0, stream>>>(cnt, diag, pairs, L);
    } else {
        hipMemsetAsync(d_out, 0, (size_t)out_size * sizeof(float), stream);
        const int total = nF * 3;
        corner_scatter_kernel<<<(total + 255) / 256, 256, 0, stream>>>(V, Fw, L, nF, N);
    }
}